// Round 1
// baseline (424.089 us; speedup 1.0000x reference)
//
#include <hip/hip_runtime.h>
#include <hip/hip_bf16.h>

#define BB 4
#define NN 1369
#define DIMM 1024
#define VDIMM 1536
#define HH 16
#define MM (BB*NN)      // 5476
#define MPAD 5504       // 43*128
#define NPAD 1408       // 22*64

typedef __attribute__((ext_vector_type(4))) float f32x4;
typedef __attribute__((ext_vector_type(8))) __bf16 bf16x8;
typedef __attribute__((ext_vector_type(4))) __bf16 bf16x4;

#define GLOAD_LDS(gsrc, ldst) \
  __builtin_amdgcn_global_load_lds((const __attribute__((address_space(1))) unsigned int*)(gsrc), \
                                   (__attribute__((address_space(3))) unsigned int*)(ldst), 16, 0, 0)

// ---------------- elementwise fp32 -> bf16 (4-wide) ----------------
__global__ __launch_bounds__(256) void cvt4(const float* __restrict__ src,
                                            __bf16* __restrict__ dst, int n4) {
  int i = blockIdx.x * blockDim.x + threadIdx.x;
  int st = gridDim.x * blockDim.x;
  for (; i < n4; i += st) {
    f32x4 v = ((const f32x4*)src)[i];
    bf16x4 o;
    o[0] = (__bf16)v[0]; o[1] = (__bf16)v[1];
    o[2] = (__bf16)v[2]; o[3] = (__bf16)v[3];
    ((bf16x4*)dst)[i] = o;
  }
}

// ---------------- RoPE tables [1369][64] ----------------
__global__ __launch_bounds__(256) void rope_tables(float* __restrict__ cosT,
                                                   float* __restrict__ sinT) {
  int idx = blockIdx.x * blockDim.x + threadIdx.x;
  if (idx >= NN * 64) return;
  int n = idx >> 6, d = idx & 63;
  int r = n / 37, c = n % 37;
  int m = (d < 32) ? (d >> 1) : ((d - 32) >> 1);
  float p = (d < 32) ? (float)r : (float)c;
  float inv = powf(10000.f, -(float)m * (1.f / 16.f));
  float a = p * inv;
  cosT[idx] = cosf(a);
  sinT[idx] = sinf(a);
}

// ---------------- mask: detect dtype, canonicalize to float [4][NPAD] ----------------
__global__ __launch_bounds__(256) void mask_prep(const void* __restrict__ mask,
                                                 float* __restrict__ maskf) {
  __shared__ int flags[2];
  int t = threadIdx.x;
  if (t < 2) flags[t] = 0;
  __syncthreads();
  const unsigned int* mw = (const unsigned int*)mask;
  for (int i = t; i < NN; i += blockDim.x) {   // first 1369 words: in-bounds for every dtype
    unsigned int w = mw[i];
    if (w == 0x3F800000u) atomicOr(&flags[1], 1);
    else if (w > 1u) atomicOr(&flags[0], 1);
  }
  __syncthreads();
  int md = flags[1] ? 2 : (flags[0] ? 1 : 0);  // 0=int32, 1=bool bytes, 2=float32
  const unsigned char* mb = (const unsigned char*)mask;
  const float* mf = (const float*)mask;
  for (int i = t; i < BB * NPAD; i += blockDim.x) {
    int b = i / NPAD, key = i % NPAD;
    float v = 0.f;
    if (key < NN) {
      int idx = b * NN + key;
      bool on = (md == 0) ? (mw[idx] != 0u) : (md == 1) ? (mb[idx] != 0) : (mf[idx] != 0.f);
      v = on ? 1.f : 0.f;
    }
    maskf[i] = v;
  }
}

// ---------------- GEMM C[m,o] = sum_i A[m,i]*W[o,i], bf16 in, fp32 acc ----------------
// EPI 0: RoPE+0.125 -> Q[b][h][n][d]    EPI 1: RoPE -> K[b][h][n][d]
// EPI 2: -> Vt[b][h][d][n]              EPI 3: +bp -> fp32 out[m][o]
template <int EPI>
__global__ __launch_bounds__(256) void gemm_bt(
    const __bf16* __restrict__ A, const __bf16* __restrict__ W, int K,
    __bf16* __restrict__ obf, float* __restrict__ of32,
    const float* __restrict__ cosT, const float* __restrict__ sinT,
    const float* __restrict__ bp) {
  __shared__ __bf16 As[128 * 32];
  __shared__ __bf16 Bs[128 * 32];
  const int tid = threadIdx.x;
  const int w = tid >> 6, l = tid & 63;
  const int tM = blockIdx.y, tN = blockIdx.x;
  const int wm = w >> 1, wn = w & 1;
  const int lo = l & 15, hi = l >> 4;

  f32x4 zero = {0.f, 0.f, 0.f, 0.f};
  f32x4 acc[4][4];
#pragma unroll
  for (int i = 0; i < 4; ++i)
#pragma unroll
    for (int j = 0; j < 4; ++j) acc[i][j] = zero;

  for (int k0 = 0; k0 < K; k0 += 32) {
    __syncthreads();
#pragma unroll
    for (int j = 0; j < 2; ++j) {
      int c = j * 4 + w;
      {
        const char* src = (const char*)A +
            ((size_t)(tM * 128 + c * 16 + (l >> 2)) * K + k0) * 2 + (l & 3) * 16;
        GLOAD_LDS(src, (char*)As + c * 1024);
      }
      {
        const char* src = (const char*)W +
            ((size_t)(tN * 128 + c * 16 + (l >> 2)) * K + k0) * 2 + (l & 3) * 16;
        GLOAD_LDS(src, (char*)Bs + c * 1024);
      }
    }
    __syncthreads();
    bf16x8 af[4], bfr[4];
#pragma unroll
    for (int mi = 0; mi < 4; ++mi)
      af[mi] = *(const bf16x8*)&As[(wm * 64 + mi * 16 + lo) * 32 + hi * 8];
#pragma unroll
    for (int ni = 0; ni < 4; ++ni)
      bfr[ni] = *(const bf16x8*)&Bs[(wn * 64 + ni * 16 + lo) * 32 + hi * 8];
#pragma unroll
    for (int mi = 0; mi < 4; ++mi)
#pragma unroll
      for (int ni = 0; ni < 4; ++ni)
        acc[mi][ni] = __builtin_amdgcn_mfma_f32_16x16x32_bf16(af[mi], bfr[ni], acc[mi][ni], 0, 0, 0);
  }

  const int m_base = tM * 128 + wm * 64;
  const int o_base = tN * 128 + wn * 64;
#pragma unroll
  for (int mi = 0; mi < 4; ++mi) {
#pragma unroll
    for (int r = 0; r < 4; ++r) {
      const int mrow = m_base + mi * 16 + hi * 4 + r;
#pragma unroll
      for (int ni = 0; ni < 4; ++ni) {
        const int col = o_base + ni * 16 + lo;
        float v = acc[mi][ni][r];
        if (EPI == 0 || EPI == 1) {
          float pprt = __shfl_xor(v, 1);  // partner (d^1), same mrow
          if (mrow < MM) {
            int b = mrow / NN, n = mrow % NN;
            int h = col >> 6, d = col & 63;
            float cs = cosT[n * 64 + d], sn = sinT[n * 64 + d];
            float out = v * cs + (((d & 1) == 0) ? -pprt : pprt) * sn;
            if (EPI == 0) out *= 0.125f;
            obf[((size_t)(b * HH + h) * NPAD + n) * 64 + d] = (__bf16)out;
          }
        } else if (EPI == 2) {
          if (mrow < MM) {
            int b = mrow / NN, n = mrow % NN;
            int h = col >> 6, d = col & 63;
            obf[((size_t)(b * HH + h) * 64 + d) * NPAD + n] = (__bf16)v;
          }
        } else {
          if (mrow < MM) of32[(size_t)mrow * DIMM + col] = v + bp[col];
        }
      }
    }
  }
}

// ---------------- flash attention: 4 waves x 16 q-rows, 32-key tiles ----------------
__global__ __launch_bounds__(256) void attn_kernel(
    const __bf16* __restrict__ Qb, const __bf16* __restrict__ Kb,
    const __bf16* __restrict__ Vtb, const float* __restrict__ maskf,
    float* __restrict__ AO) {
  __shared__ __bf16 Ks[32 * 64];
  __shared__ __bf16 Vs[64 * 32];
  __shared__ __bf16 Ps[4][16 * 32];
  const int tid = threadIdx.x;
  const int w = tid >> 6, l = tid & 63;
  const int lo = l & 15, hi = l >> 4;
  const int bh = blockIdx.x;  // b*16+h
  const int qt = blockIdx.y;
  const int b = bh >> 4;
  const int q0 = qt * 64 + w * 16;

  const __bf16* Qp = Qb + ((size_t)bh * NPAD + q0) * 64;
  bf16x8 qf0 = *(const bf16x8*)&Qp[lo * 64 + hi * 8];
  bf16x8 qf1 = *(const bf16x8*)&Qp[lo * 64 + 32 + hi * 8];

  f32x4 zero = {0.f, 0.f, 0.f, 0.f};
  f32x4 O0 = zero, O1 = zero, O2 = zero, O3 = zero;
  float mr[4], lr[4];
#pragma unroll
  for (int r = 0; r < 4; ++r) { mr[r] = -__builtin_inff(); lr[r] = 0.f; }
  const float* mk = maskf + b * NPAD;

  for (int k0 = 0; k0 < NPAD; k0 += 32) {
    __syncthreads();
    {
      const char* src = (const char*)Kb + ((size_t)bh * NPAD + k0) * 128 + w * 1024 + l * 16;
      GLOAD_LDS(src, (char*)Ks + w * 1024);
    }
    {
      const char* src = (const char*)Vtb +
          ((size_t)(bh * 64 + w * 16 + (l >> 2)) * NPAD + k0) * 2 + (l & 3) * 16;
      GLOAD_LDS(src, (char*)Vs + w * 1024);
    }
    __syncthreads();

    f32x4 S0 = zero, S1 = zero;
    {
      bf16x8 kf;
      kf = *(const bf16x8*)&Ks[(lo)*64 + hi * 8];
      S0 = __builtin_amdgcn_mfma_f32_16x16x32_bf16(qf0, kf, S0, 0, 0, 0);
      kf = *(const bf16x8*)&Ks[(lo)*64 + 32 + hi * 8];
      S0 = __builtin_amdgcn_mfma_f32_16x16x32_bf16(qf1, kf, S0, 0, 0, 0);
      kf = *(const bf16x8*)&Ks[(16 + lo) * 64 + hi * 8];
      S1 = __builtin_amdgcn_mfma_f32_16x16x32_bf16(qf0, kf, S1, 0, 0, 0);
      kf = *(const bf16x8*)&Ks[(16 + lo) * 64 + 32 + hi * 8];
      S1 = __builtin_amdgcn_mfma_f32_16x16x32_bf16(qf1, kf, S1, 0, 0, 0);
    }
    float b0 = mk[k0 + lo], b1 = mk[k0 + 16 + lo];
#pragma unroll
    for (int r = 0; r < 4; ++r) {
      if (b0 == 0.f) S0[r] = -1e30f;
      if (b1 == 0.f) S1[r] = -1e30f;
    }
#pragma unroll
    for (int r = 0; r < 4; ++r) {
      float mx = fmaxf(S0[r], S1[r]);
      mx = fmaxf(mx, __shfl_xor(mx, 1));
      mx = fmaxf(mx, __shfl_xor(mx, 2));
      mx = fmaxf(mx, __shfl_xor(mx, 4));
      mx = fmaxf(mx, __shfl_xor(mx, 8));
      float mnew = fmaxf(mr[r], mx);
      float corr = __expf(mr[r] - mnew);  // exp(-inf)=0 on first tile
      mr[r] = mnew;
      float p0 = __expf(S0[r] - mnew);
      float p1 = __expf(S1[r] - mnew);
      float rs = p0 + p1;
      rs += __shfl_xor(rs, 1); rs += __shfl_xor(rs, 2);
      rs += __shfl_xor(rs, 4); rs += __shfl_xor(rs, 8);
      lr[r] = lr[r] * corr + rs;
      O0[r] *= corr; O1[r] *= corr; O2[r] *= corr; O3[r] *= corr;
      Ps[w][(hi * 4 + r) * 32 + lo] = (__bf16)p0;
      Ps[w][(hi * 4 + r) * 32 + 16 + lo] = (__bf16)p1;
    }
    bf16x8 pf = *(const bf16x8*)&Ps[w][lo * 32 + hi * 8];
    bf16x8 vf;
    vf = *(const bf16x8*)&Vs[(lo)*32 + hi * 8];
    O0 = __builtin_amdgcn_mfma_f32_16x16x32_bf16(pf, vf, O0, 0, 0, 0);
    vf = *(const bf16x8*)&Vs[(16 + lo) * 32 + hi * 8];
    O1 = __builtin_amdgcn_mfma_f32_16x16x32_bf16(pf, vf, O1, 0, 0, 0);
    vf = *(const bf16x8*)&Vs[(32 + lo) * 32 + hi * 8];
    O2 = __builtin_amdgcn_mfma_f32_16x16x32_bf16(pf, vf, O2, 0, 0, 0);
    vf = *(const bf16x8*)&Vs[(48 + lo) * 32 + hi * 8];
    O3 = __builtin_amdgcn_mfma_f32_16x16x32_bf16(pf, vf, O3, 0, 0, 0);
  }

  const int h = bh & 15;
#pragma unroll
  for (int r = 0; r < 4; ++r) {
    int n = q0 + hi * 4 + r;
    if (n < NN) {
      float inv = 1.f / lr[r];
      float* dst = AO + ((size_t)(b * NN + n)) * DIMM + h * 64;
      dst[0 + lo]  = O0[r] * inv;
      dst[16 + lo] = O1[r] * inv;
      dst[32 + lo] = O2[r] * inv;
      dst[48 + lo] = O3[r] * inv;
    }
  }
}

// ---------------- LayerNorm over 1024, fp32 in, bf16 out ----------------
__global__ __launch_bounds__(256) void ln_kernel(
    const float* __restrict__ AO, const float* __restrict__ g,
    const float* __restrict__ be, __bf16* __restrict__ outb) {
  const int row = blockIdx.x;
  const int t = threadIdx.x;
  const float* x = AO + (size_t)row * DIMM;
  f32x4 v = ((const f32x4*)x)[t];
  float s = v[0] + v[1] + v[2] + v[3];
  float sq = v[0] * v[0] + v[1] * v[1] + v[2] * v[2] + v[3] * v[3];
#pragma unroll
  for (int m = 1; m < 64; m <<= 1) { s += __shfl_xor(s, m); sq += __shfl_xor(sq, m); }
  __shared__ float ss[4], ssq[4];
  int w = t >> 6, l = t & 63;
  if (l == 0) { ss[w] = s; ssq[w] = sq; }
  __syncthreads();
  s = ss[0] + ss[1] + ss[2] + ss[3];
  sq = ssq[0] + ssq[1] + ssq[2] + ssq[3];
  float mean = s * (1.f / 1024.f);
  float var = sq * (1.f / 1024.f) - mean * mean;
  float rstd = rsqrtf(var + 1e-5f);
  __bf16* o = outb + (size_t)row * DIMM + t * 4;
  const float* gp = g + t * 4;
  const float* bp2 = be + t * 4;
#pragma unroll
  for (int j = 0; j < 4; ++j) o[j] = (__bf16)((v[j] - mean) * rstd * gp[j] + bp2[j]);
}

// ---------------- launch ----------------
extern "C" void kernel_launch(void* const* d_in, const int* in_sizes, int n_in,
                              void* d_out, int out_size, void* d_ws, size_t ws_size,
                              hipStream_t stream) {
  const float* x   = (const float*)d_in[0];
  const float* val = (const float*)d_in[1];
  const void*  msk = d_in[2];
  const float* wq  = (const float*)d_in[3];
  const float* wk  = (const float*)d_in[4];
  const float* wv  = (const float*)d_in[5];
  const float* lng = (const float*)d_in[6];
  const float* lnb = (const float*)d_in[7];
  const float* wp  = (const float*)d_in[8];
  const float* bpv = (const float*)d_in[9];
  float* out = (float*)d_out;

  char* ws = (char*)d_ws;
  size_t off = 0;
  auto alloc = [&](size_t bytes) -> char* {
    char* p = ws + off;
    off += (bytes + 255) & ~(size_t)255;
    return p;
  };
  __bf16* xb  = (__bf16*)alloc((size_t)MPAD * 1024 * 2);  // also reused as LN output
  __bf16* vb  = (__bf16*)alloc((size_t)MPAD * 1536 * 2);
  __bf16* wqb = (__bf16*)alloc((size_t)1024 * 1024 * 2);
  __bf16* wkb = (__bf16*)alloc((size_t)1024 * 1536 * 2);
  __bf16* wvb = (__bf16*)alloc((size_t)1024 * 1536 * 2);
  __bf16* wpb = (__bf16*)alloc((size_t)1024 * 1024 * 2);
  __bf16* Qb  = (__bf16*)alloc((size_t)64 * NPAD * 64 * 2);
  __bf16* Kb  = (__bf16*)alloc((size_t)64 * NPAD * 64 * 2);
  __bf16* Vtb = (__bf16*)alloc((size_t)64 * 64 * NPAD * 2);
  float* AO   = (float*)alloc((size_t)MM * 1024 * 4);
  float* cosT = (float*)alloc((size_t)NN * 64 * 4);
  float* sinT = (float*)alloc((size_t)NN * 64 * 4);
  float* maskf = (float*)alloc((size_t)BB * NPAD * 4);

  // zero padded regions (pad rows of A-matrices; full Q/K/Vt so key-pads are 0)
  hipMemsetAsync(xb + (size_t)MM * 1024, 0, (size_t)(MPAD - MM) * 1024 * 2, stream);
  hipMemsetAsync(vb + (size_t)MM * 1536, 0, (size_t)(MPAD - MM) * 1536 * 2, stream);
  hipMemsetAsync(Qb, 0, (size_t)64 * NPAD * 64 * 2, stream);
  hipMemsetAsync(Kb, 0, (size_t)64 * NPAD * 64 * 2, stream);
  hipMemsetAsync(Vtb, 0, (size_t)64 * 64 * NPAD * 2, stream);

  cvt4<<<1024, 256, 0, stream>>>(x, xb, MM * 1024 / 4);
  cvt4<<<1024, 256, 0, stream>>>(val, vb, MM * 1536 / 4);
  cvt4<<<512, 256, 0, stream>>>(wq, wqb, 1024 * 1024 / 4);
  cvt4<<<512, 256, 0, stream>>>(wk, wkb, 1024 * 1536 / 4);
  cvt4<<<512, 256, 0, stream>>>(wv, wvb, 1024 * 1536 / 4);
  cvt4<<<512, 256, 0, stream>>>(wp, wpb, 1024 * 1024 / 4);
  rope_tables<<<(NN * 64 + 255) / 256, 256, 0, stream>>>(cosT, sinT);
  mask_prep<<<1, 256, 0, stream>>>(msk, maskf);

  dim3 gg(8, 43);
  gemm_bt<0><<<gg, 256, 0, stream>>>(xb, wqb, 1024, Qb, nullptr, cosT, sinT, nullptr);
  gemm_bt<1><<<gg, 256, 0, stream>>>(vb, wkb, 1536, Kb, nullptr, cosT, sinT, nullptr);
  gemm_bt<2><<<gg, 256, 0, stream>>>(vb, wvb, 1536, Vtb, nullptr, nullptr, nullptr, nullptr);

  attn_kernel<<<dim3(64, 22), 256, 0, stream>>>(Qb, Kb, Vtb, maskf, AO);

  ln_kernel<<<MM, 256, 0, stream>>>(AO, lng, lnb, xb);  // reuse xb as LN output

  gemm_bt<3><<<gg, 256, 0, stream>>>(xb, wpb, 1024, nullptr, out, nullptr, nullptr, bpv);
}

// Round 2
// 361.758 us; speedup vs baseline: 1.1723x; 1.1723x over previous
//
#include <hip/hip_runtime.h>
#include <hip/hip_bf16.h>

#define BB 4
#define NN 1369
#define DIMM 1024
#define VDIMM 1536
#define HH 16
#define MM (BB*NN)      // 5476
#define MPAD 5504       // 43*128
#define NPAD 1408       // 22*64
#define KVB 64
#define NT (NPAD/KVB)   // 22

typedef __attribute__((ext_vector_type(4))) float f32x4;
typedef __attribute__((ext_vector_type(8))) __bf16 bf16x8;
typedef __attribute__((ext_vector_type(4))) __bf16 bf16x4;

#define GLOAD_LDS(gsrc, ldst) \
  __builtin_amdgcn_global_load_lds((const __attribute__((address_space(1))) unsigned int*)(gsrc), \
                                   (__attribute__((address_space(3))) unsigned int*)(ldst), 16, 0, 0)

// ---------------- elementwise fp32 -> bf16 (4-wide) ----------------
__global__ __launch_bounds__(256) void cvt4(const float* __restrict__ src,
                                            __bf16* __restrict__ dst, int n4) {
  int i = blockIdx.x * blockDim.x + threadIdx.x;
  int st = gridDim.x * blockDim.x;
  for (; i < n4; i += st) {
    f32x4 v = ((const f32x4*)src)[i];
    bf16x4 o;
    o[0] = (__bf16)v[0]; o[1] = (__bf16)v[1];
    o[2] = (__bf16)v[2]; o[3] = (__bf16)v[3];
    ((bf16x4*)dst)[i] = o;
  }
}

// ---------------- RoPE tables [1369][64] ----------------
__global__ __launch_bounds__(256) void rope_tables(float* __restrict__ cosT,
                                                   float* __restrict__ sinT) {
  int idx = blockIdx.x * blockDim.x + threadIdx.x;
  if (idx >= NN * 64) return;
  int n = idx >> 6, d = idx & 63;
  int r = n / 37, c = n % 37;
  int m = (d < 32) ? (d >> 1) : ((d - 32) >> 1);
  float p = (d < 32) ? (float)r : (float)c;
  float inv = powf(10000.f, -(float)m * (1.f / 16.f));
  float a = p * inv;
  cosT[idx] = cosf(a);
  sinT[idx] = sinf(a);
}

// ---------------- mask: detect dtype, canonicalize to ADDITIVE float [4][NPAD] ----------------
// on -> 0.0f ; off (or pad) -> -1e30f
__global__ __launch_bounds__(256) void mask_prep(const void* __restrict__ mask,
                                                 float* __restrict__ maskA) {
  __shared__ int flags[2];
  int t = threadIdx.x;
  if (t < 2) flags[t] = 0;
  __syncthreads();
  const unsigned int* mw = (const unsigned int*)mask;
  for (int i = t; i < NN; i += blockDim.x) {   // first 1369 words: in-bounds for every dtype
    unsigned int w = mw[i];
    if (w == 0x3F800000u) atomicOr(&flags[1], 1);
    else if (w > 1u) atomicOr(&flags[0], 1);
  }
  __syncthreads();
  int md = flags[1] ? 2 : (flags[0] ? 1 : 0);  // 0=int32, 1=bool bytes, 2=float32
  const unsigned char* mb = (const unsigned char*)mask;
  const float* mf = (const float*)mask;
  for (int i = t; i < BB * NPAD; i += blockDim.x) {
    int b = i / NPAD, key = i % NPAD;
    float v = -1e30f;
    if (key < NN) {
      int idx = b * NN + key;
      bool on = (md == 0) ? (mw[idx] != 0u) : (md == 1) ? (mb[idx] != 0) : (mf[idx] != 0.f);
      if (on) v = 0.f;
    }
    maskA[i] = v;
  }
}

// ---------------- GEMM C[m,o] = sum_i A[m,i]*W[o,i], bf16 in, fp32 acc ----------------
// EPI 0: RoPE+0.125 -> Q[b][h][n][d]    EPI 1: RoPE -> K[b][h][n][d]
// EPI 2: -> Vt[b][h][d][n]              EPI 3: +bp -> fp32 out[m][o]
template <int EPI>
__global__ __launch_bounds__(256) void gemm_bt(
    const __bf16* __restrict__ A, const __bf16* __restrict__ W, int K,
    __bf16* __restrict__ obf, float* __restrict__ of32,
    const float* __restrict__ cosT, const float* __restrict__ sinT,
    const float* __restrict__ bp) {
  __shared__ __bf16 As[128 * 32];
  __shared__ __bf16 Bs[128 * 32];
  const int tid = threadIdx.x;
  const int w = tid >> 6, l = tid & 63;
  const int tM = blockIdx.y, tN = blockIdx.x;
  const int wm = w >> 1, wn = w & 1;
  const int lo = l & 15, hi = l >> 4;

  f32x4 zero = {0.f, 0.f, 0.f, 0.f};
  f32x4 acc[4][4];
#pragma unroll
  for (int i = 0; i < 4; ++i)
#pragma unroll
    for (int j = 0; j < 4; ++j) acc[i][j] = zero;

  for (int k0 = 0; k0 < K; k0 += 32) {
    __syncthreads();
#pragma unroll
    for (int j = 0; j < 2; ++j) {
      int c = j * 4 + w;
      {
        const char* src = (const char*)A +
            ((size_t)(tM * 128 + c * 16 + (l >> 2)) * K + k0) * 2 + (l & 3) * 16;
        GLOAD_LDS(src, (char*)As + c * 1024);
      }
      {
        const char* src = (const char*)W +
            ((size_t)(tN * 128 + c * 16 + (l >> 2)) * K + k0) * 2 + (l & 3) * 16;
        GLOAD_LDS(src, (char*)Bs + c * 1024);
      }
    }
    __syncthreads();
    bf16x8 af[4], bfr[4];
#pragma unroll
    for (int mi = 0; mi < 4; ++mi)
      af[mi] = *(const bf16x8*)&As[(wm * 64 + mi * 16 + lo) * 32 + hi * 8];
#pragma unroll
    for (int ni = 0; ni < 4; ++ni)
      bfr[ni] = *(const bf16x8*)&Bs[(wn * 64 + ni * 16 + lo) * 32 + hi * 8];
#pragma unroll
    for (int mi = 0; mi < 4; ++mi)
#pragma unroll
      for (int ni = 0; ni < 4; ++ni)
        acc[mi][ni] = __builtin_amdgcn_mfma_f32_16x16x32_bf16(af[mi], bfr[ni], acc[mi][ni], 0, 0, 0);
  }

  const int m_base = tM * 128 + wm * 64;
  const int o_base = tN * 128 + wn * 64;
#pragma unroll
  for (int mi = 0; mi < 4; ++mi) {
#pragma unroll
    for (int r = 0; r < 4; ++r) {
      const int mrow = m_base + mi * 16 + hi * 4 + r;
#pragma unroll
      for (int ni = 0; ni < 4; ++ni) {
        const int col = o_base + ni * 16 + lo;
        float v = acc[mi][ni][r];
        if (EPI == 0 || EPI == 1) {
          float pprt = __shfl_xor(v, 1);  // partner (d^1), same mrow
          if (mrow < MM) {
            int b = mrow / NN, n = mrow % NN;
            int h = col >> 6, d = col & 63;
            float cs = cosT[n * 64 + d], sn = sinT[n * 64 + d];
            float out = v * cs + (((d & 1) == 0) ? -pprt : pprt) * sn;
            if (EPI == 0) out *= 0.125f;
            obf[((size_t)(b * HH + h) * NPAD + n) * 64 + d] = (__bf16)out;
          }
        } else if (EPI == 2) {
          if (mrow < MM) {
            int b = mrow / NN, n = mrow % NN;
            int h = col >> 6, d = col & 63;
            obf[((size_t)(b * HH + h) * 64 + d) * NPAD + n] = (__bf16)v;
          }
        } else {
          if (mrow < MM) of32[(size_t)mrow * DIMM + col] = v + bp[col];
        }
      }
    }
  }
}

// ---------------- flash attention v2 ----------------
// 4 waves x 16 q-rows, 64-key tiles, double-buffered K/V staging (2-phase),
// XOR-swizzled LDS (linear gload dest + inverse-swizzled global source),
// additive mask, setprio around MFMA.
__global__ __launch_bounds__(256) void attn_kernel(
    const __bf16* __restrict__ Qb, const __bf16* __restrict__ Kb,
    const __bf16* __restrict__ Vtb, const float* __restrict__ maskA,
    float* __restrict__ AO) {
  __shared__ __bf16 Ks[2][64 * 64];
  __shared__ __bf16 Vs[2][64 * 64];
  __shared__ __bf16 Ps[4][16 * 64];
  const int tid = threadIdx.x;
  const int w = tid >> 6, l = tid & 63;
  const int lo = l & 15, hi = l >> 4;

  // XCD-aware swizzle: 1408 blocks, 8 XCDs, 176 consecutive orig-ids per XCD
  // orig = bh*NT + qt  -> one XCD covers 8 heads' worth of K/V (2.8MB < 4MB L2)
  const int i = blockIdx.x;
  const int orig = (i & 7) * 176 + (i >> 3);
  const int bh = orig / NT;
  const int qt = orig % NT;
  const int b = bh >> 4;
  const int q0 = qt * 64 + w * 16;

  const __bf16* Qp = Qb + ((size_t)bh * NPAD + q0) * 64;
  bf16x8 qf0 = *(const bf16x8*)&Qp[lo * 64 + hi * 8];
  bf16x8 qf1 = *(const bf16x8*)&Qp[lo * 64 + 32 + hi * 8];

  // staging: LDS linear dest (wave-uniform base + lane*16), source pre-swizzled
  const int row8 = l >> 3;                    // row within 8-row stripe
  const int swz16 = ((l & 7) ^ row8) << 4;    // swizzled 16B-chunk byte offset
  const int lo7 = lo & 7;

  f32x4 zero = {0.f, 0.f, 0.f, 0.f};
  f32x4 O[4];
#pragma unroll
  for (int n = 0; n < 4; ++n) O[n] = zero;
  float mr[4], lr[4];
#pragma unroll
  for (int r = 0; r < 4; ++r) { mr[r] = -1e30f; lr[r] = 0.f; }
  const float* mk = maskA + b * NPAD;

#define STAGE(buf, k0)                                                                   \
  {                                                                                      \
    _Pragma("unroll") for (int j = 0; j < 2; ++j) {                                      \
      const int rbase = (j * 4 + w) * 8;                                                 \
      const char* ksrc = (const char*)Kb +                                               \
          ((size_t)bh * NPAD + (k0) + rbase + row8) * 128 + swz16;                       \
      GLOAD_LDS(ksrc, (char*)&Ks[buf][0] + rbase * 128);                                 \
      const char* vsrc = (const char*)Vtb +                                              \
          ((size_t)(bh * 64 + rbase + row8) * NPAD + (k0)) * 2 + swz16;                  \
      GLOAD_LDS(vsrc, (char*)&Vs[buf][0] + rbase * 128);                                 \
    }                                                                                    \
  }

  STAGE(0, 0);
  __syncthreads();
  int cur = 0;

  for (int t = 0; t < NT; ++t) {
    if (t + 1 < NT) STAGE(cur ^ 1, (t + 1) * KVB);  // overlaps with compute below

    const __bf16* KB = &Ks[cur][0];
    const __bf16* VB = &Vs[cur][0];

    // ---- S = Q K^T (64 keys), swizzled reads ----
    f32x4 S[4];
    __builtin_amdgcn_s_setprio(1);
#pragma unroll
    for (int c = 0; c < 4; ++c) {
      const int kr = c * 16 + lo;
      bf16x8 kfa = *(const bf16x8*)&KB[kr * 64 + ((hi ^ lo7) * 8)];
      bf16x8 kfb = *(const bf16x8*)&KB[kr * 64 + (((hi + 4) ^ lo7) * 8)];
      f32x4 s = zero;
      s = __builtin_amdgcn_mfma_f32_16x16x32_bf16(qf0, kfa, s, 0, 0, 0);
      s = __builtin_amdgcn_mfma_f32_16x16x32_bf16(qf1, kfb, s, 0, 0, 0);
      S[c] = s;
    }
    __builtin_amdgcn_s_setprio(0);
#pragma unroll
    for (int c = 0; c < 4; ++c) {
      float bc = mk[t * KVB + c * 16 + lo];   // additive: 0 or -1e30
#pragma unroll
      for (int r = 0; r < 4; ++r) S[c][r] += bc;
    }

    // ---- online softmax (per q-row r, reduce over lo lanes) ----
#pragma unroll
    for (int r = 0; r < 4; ++r) {
      float mx = fmaxf(fmaxf(S[0][r], S[1][r]), fmaxf(S[2][r], S[3][r]));
      mx = fmaxf(mx, __shfl_xor(mx, 1));
      mx = fmaxf(mx, __shfl_xor(mx, 2));
      mx = fmaxf(mx, __shfl_xor(mx, 4));
      mx = fmaxf(mx, __shfl_xor(mx, 8));
      const float mnew = fmaxf(mr[r], mx);
      const float corr = __expf(mr[r] - mnew);
      mr[r] = mnew;
      const int q = hi * 4 + r;
      float rs = 0.f;
#pragma unroll
      for (int c = 0; c < 4; ++c) {
        float p = __expf(S[c][r] - mnew);
        rs += p;
        const int colb = (c * 32 + lo * 2) ^ ((q & 7) << 4);   // swizzled P store
        *(__bf16*)((char*)&Ps[w][0] + q * 128 + colb) = (__bf16)p;
      }
      rs += __shfl_xor(rs, 1); rs += __shfl_xor(rs, 2);
      rs += __shfl_xor(rs, 4); rs += __shfl_xor(rs, 8);
      lr[r] = lr[r] * corr + rs;
#pragma unroll
      for (int n = 0; n < 4; ++n) O[n][r] *= corr;
    }

    // ---- O += P V (swizzled reads of own-wave Ps and Vs) ----
    bf16x8 pf0 = *(const bf16x8*)((char*)&Ps[w][0] + lo * 128 + ((hi * 16) ^ (lo7 << 4)));
    bf16x8 pf1 = *(const bf16x8*)((char*)&Ps[w][0] + lo * 128 + ((64 + hi * 16) ^ (lo7 << 4)));
    __builtin_amdgcn_s_setprio(1);
#pragma unroll
    for (int n = 0; n < 4; ++n) {
      const int vr = n * 16 + lo;
      bf16x8 vfa = *(const bf16x8*)&VB[vr * 64 + ((hi ^ lo7) * 8)];
      bf16x8 vfb = *(const bf16x8*)&VB[vr * 64 + (((hi + 4) ^ lo7) * 8)];
      O[n] = __builtin_amdgcn_mfma_f32_16x16x32_bf16(pf0, vfa, O[n], 0, 0, 0);
      O[n] = __builtin_amdgcn_mfma_f32_16x16x32_bf16(pf1, vfb, O[n], 0, 0, 0);
    }
    __builtin_amdgcn_s_setprio(0);

    __syncthreads();   // drains next-tile staging (vmcnt) + protects buffer swap
    cur ^= 1;
  }
#undef STAGE

  const int h = bh & 15;
#pragma unroll
  for (int r = 0; r < 4; ++r) {
    const int n = q0 + hi * 4 + r;
    if (n < NN) {
      const float inv = 1.f / lr[r];
      float* dst = AO + ((size_t)(b * NN + n)) * DIMM + h * 64;
#pragma unroll
      for (int g = 0; g < 4; ++g) dst[g * 16 + lo] = O[g][r] * inv;
    }
  }
}

// ---------------- LayerNorm over 1024, fp32 in, bf16 out ----------------
__global__ __launch_bounds__(256) void ln_kernel(
    const float* __restrict__ AO, const float* __restrict__ g,
    const float* __restrict__ be, __bf16* __restrict__ outb) {
  const int row = blockIdx.x;
  const int t = threadIdx.x;
  const float* x = AO + (size_t)row * DIMM;
  f32x4 v = ((const f32x4*)x)[t];
  float s = v[0] + v[1] + v[2] + v[3];
  float sq = v[0] * v[0] + v[1] * v[1] + v[2] * v[2] + v[3] * v[3];
#pragma unroll
  for (int m = 1; m < 64; m <<= 1) { s += __shfl_xor(s, m); sq += __shfl_xor(sq, m); }
  __shared__ float ss[4], ssq[4];
  int w = t >> 6, l = t & 63;
  if (l == 0) { ss[w] = s; ssq[w] = sq; }
  __syncthreads();
  s = ss[0] + ss[1] + ss[2] + ss[3];
  sq = ssq[0] + ssq[1] + ssq[2] + ssq[3];
  float mean = s * (1.f / 1024.f);
  float var = sq * (1.f / 1024.f) - mean * mean;
  float rstd = rsqrtf(var + 1e-5f);
  __bf16* o = outb + (size_t)row * DIMM + t * 4;
  const float* gp = g + t * 4;
  const float* bp2 = be + t * 4;
#pragma unroll
  for (int j = 0; j < 4; ++j) o[j] = (__bf16)((v[j] - mean) * rstd * gp[j] + bp2[j]);
}

// ---------------- launch ----------------
extern "C" void kernel_launch(void* const* d_in, const int* in_sizes, int n_in,
                              void* d_out, int out_size, void* d_ws, size_t ws_size,
                              hipStream_t stream) {
  const float* x   = (const float*)d_in[0];
  const float* val = (const float*)d_in[1];
  const void*  msk = d_in[2];
  const float* wq  = (const float*)d_in[3];
  const float* wk  = (const float*)d_in[4];
  const float* wv  = (const float*)d_in[5];
  const float* lng = (const float*)d_in[6];
  const float* lnb = (const float*)d_in[7];
  const float* wp  = (const float*)d_in[8];
  const float* bpv = (const float*)d_in[9];
  float* out = (float*)d_out;

  char* ws = (char*)d_ws;
  size_t off = 0;
  auto alloc = [&](size_t bytes) -> char* {
    char* p = ws + off;
    off += (bytes + 255) & ~(size_t)255;
    return p;
  };
  __bf16* xb  = (__bf16*)alloc((size_t)MPAD * 1024 * 2);  // also reused as LN output
  __bf16* vb  = (__bf16*)alloc((size_t)MPAD * 1536 * 2);
  __bf16* wqb = (__bf16*)alloc((size_t)1024 * 1024 * 2);
  __bf16* wkb = (__bf16*)alloc((size_t)1024 * 1536 * 2);
  __bf16* wvb = (__bf16*)alloc((size_t)1024 * 1536 * 2);
  __bf16* wpb = (__bf16*)alloc((size_t)1024 * 1024 * 2);
  __bf16* Qb  = (__bf16*)alloc((size_t)64 * NPAD * 64 * 2);
  __bf16* Kb  = (__bf16*)alloc((size_t)64 * NPAD * 64 * 2);
  __bf16* Vtb = (__bf16*)alloc((size_t)64 * 64 * NPAD * 2);
  float* AO   = (float*)alloc((size_t)MM * 1024 * 4);
  float* cosT = (float*)alloc((size_t)NN * 64 * 4);
  float* sinT = (float*)alloc((size_t)NN * 64 * 4);
  float* maskA = (float*)alloc((size_t)BB * NPAD * 4);

  // zero padded regions (pad rows of A-matrices; full Q/K/Vt so key-pads are benign)
  hipMemsetAsync(xb + (size_t)MM * 1024, 0, (size_t)(MPAD - MM) * 1024 * 2, stream);
  hipMemsetAsync(vb + (size_t)MM * 1536, 0, (size_t)(MPAD - MM) * 1536 * 2, stream);
  hipMemsetAsync(Qb, 0, (size_t)64 * NPAD * 64 * 2, stream);
  hipMemsetAsync(Kb, 0, (size_t)64 * NPAD * 64 * 2, stream);
  hipMemsetAsync(Vtb, 0, (size_t)64 * 64 * NPAD * 2, stream);

  cvt4<<<1024, 256, 0, stream>>>(x, xb, MM * 1024 / 4);
  cvt4<<<1024, 256, 0, stream>>>(val, vb, MM * 1536 / 4);
  cvt4<<<512, 256, 0, stream>>>(wq, wqb, 1024 * 1024 / 4);
  cvt4<<<512, 256, 0, stream>>>(wk, wkb, 1024 * 1536 / 4);
  cvt4<<<512, 256, 0, stream>>>(wv, wvb, 1024 * 1536 / 4);
  cvt4<<<512, 256, 0, stream>>>(wp, wpb, 1024 * 1024 / 4);
  rope_tables<<<(NN * 64 + 255) / 256, 256, 0, stream>>>(cosT, sinT);
  mask_prep<<<1, 256, 0, stream>>>(msk, maskA);

  dim3 gg(8, 43);
  gemm_bt<0><<<gg, 256, 0, stream>>>(xb, wqb, 1024, Qb, nullptr, cosT, sinT, nullptr);
  gemm_bt<1><<<gg, 256, 0, stream>>>(vb, wkb, 1536, Kb, nullptr, cosT, sinT, nullptr);
  gemm_bt<2><<<gg, 256, 0, stream>>>(vb, wvb, 1536, Vtb, nullptr, nullptr, nullptr, nullptr);

  attn_kernel<<<dim3(64 * NT), 256, 0, stream>>>(Qb, Kb, Vtb, maskA, AO);

  ln_kernel<<<MM, 256, 0, stream>>>(AO, lng, lnb, xb);  // reuse xb as LN output

  gemm_bt<3><<<gg, 256, 0, stream>>>(xb, wpb, 1024, nullptr, out, nullptr, nullptr, bpv);
}

// Round 3
// 314.150 us; speedup vs baseline: 1.3500x; 1.1515x over previous
//
#include <hip/hip_runtime.h>
#include <hip/hip_bf16.h>

#define BB 4
#define NN 1369
#define DIMM 1024
#define VDIMM 1536
#define HH 16
#define MM (BB*NN)      // 5476
#define MPAD 5504       // 43*128
#define NPAD 1408       // 22*64
#define KVB 64
#define NT (NPAD/KVB)   // 22

typedef __attribute__((ext_vector_type(4))) float f32x4;
typedef __attribute__((ext_vector_type(8))) __bf16 bf16x8;
typedef __attribute__((ext_vector_type(4))) __bf16 bf16x4;

#define GLOAD_LDS(gsrc, ldst) \
  __builtin_amdgcn_global_load_lds((const __attribute__((address_space(1))) unsigned int*)(gsrc), \
                                   (__attribute__((address_space(3))) unsigned int*)(ldst), 16, 0, 0)

// ---------------- elementwise fp32 -> bf16 (4-wide) ----------------
__global__ __launch_bounds__(256) void cvt4(const float* __restrict__ src,
                                            __bf16* __restrict__ dst, int n4) {
  int i = blockIdx.x * blockDim.x + threadIdx.x;
  int st = gridDim.x * blockDim.x;
  for (; i < n4; i += st) {
    f32x4 v = ((const f32x4*)src)[i];
    bf16x4 o;
    o[0] = (__bf16)v[0]; o[1] = (__bf16)v[1];
    o[2] = (__bf16)v[2]; o[3] = (__bf16)v[3];
    ((bf16x4*)dst)[i] = o;
  }
}

// ---------------- RoPE tables [1369][64] ----------------
__global__ __launch_bounds__(256) void rope_tables(float* __restrict__ cosT,
                                                   float* __restrict__ sinT) {
  int idx = blockIdx.x * blockDim.x + threadIdx.x;
  if (idx >= NN * 64) return;
  int n = idx >> 6, d = idx & 63;
  int r = n / 37, c = n % 37;
  int m = (d < 32) ? (d >> 1) : ((d - 32) >> 1);
  float p = (d < 32) ? (float)r : (float)c;
  float inv = powf(10000.f, -(float)m * (1.f / 16.f));
  float a = p * inv;
  cosT[idx] = cosf(a);
  sinT[idx] = sinf(a);
}

// ---------------- mask: detect dtype, canonicalize to ADDITIVE float [4][NPAD] ----------------
// on -> 0.0f ; off (or pad) -> -1e30f
__global__ __launch_bounds__(256) void mask_prep(const void* __restrict__ mask,
                                                 float* __restrict__ maskA) {
  __shared__ int flags[2];
  int t = threadIdx.x;
  if (t < 2) flags[t] = 0;
  __syncthreads();
  const unsigned int* mw = (const unsigned int*)mask;
  for (int i = t; i < NN; i += blockDim.x) {   // first 1369 words: in-bounds for every dtype
    unsigned int w = mw[i];
    if (w == 0x3F800000u) atomicOr(&flags[1], 1);
    else if (w > 1u) atomicOr(&flags[0], 1);
  }
  __syncthreads();
  int md = flags[1] ? 2 : (flags[0] ? 1 : 0);  // 0=int32, 1=bool bytes, 2=float32
  const unsigned char* mb = (const unsigned char*)mask;
  const float* mf = (const float*)mask;
  for (int i = t; i < BB * NPAD; i += blockDim.x) {
    int b = i / NPAD, key = i % NPAD;
    float v = -1e30f;
    if (key < NN) {
      int idx = b * NN + key;
      bool on = (md == 0) ? (mw[idx] != 0u) : (md == 1) ? (mb[idx] != 0) : (mf[idx] != 0.f);
      if (on) v = 0.f;
    }
    maskA[i] = v;
  }
}

// ---------------- GEMM C[m,o] = sum_i A[m,i]*W[o,i], bf16 in, fp32 acc ----------------
// EPI 0: RoPE+0.125 -> Q[b][h][n][d]    EPI 1: RoPE -> K[b][h][n][d]
// EPI 2: -> Vt[b][h][d][n]              EPI 3: +bp -> fp32 out[m][o]
template <int EPI>
__global__ __launch_bounds__(256) void gemm_bt(
    const __bf16* __restrict__ A, const __bf16* __restrict__ W, int K,
    __bf16* __restrict__ obf, float* __restrict__ of32,
    const float* __restrict__ cosT, const float* __restrict__ sinT,
    const float* __restrict__ bp) {
  __shared__ __bf16 As[128 * 32];
  __shared__ __bf16 Bs[128 * 32];
  const int tid = threadIdx.x;
  const int w = tid >> 6, l = tid & 63;
  const int tM = blockIdx.y, tN = blockIdx.x;
  const int wm = w >> 1, wn = w & 1;
  const int lo = l & 15, hi = l >> 4;

  f32x4 zero = {0.f, 0.f, 0.f, 0.f};
  f32x4 acc[4][4];
#pragma unroll
  for (int i = 0; i < 4; ++i)
#pragma unroll
    for (int j = 0; j < 4; ++j) acc[i][j] = zero;

  for (int k0 = 0; k0 < K; k0 += 32) {
    __syncthreads();
#pragma unroll
    for (int j = 0; j < 2; ++j) {
      int c = j * 4 + w;
      {
        const char* src = (const char*)A +
            ((size_t)(tM * 128 + c * 16 + (l >> 2)) * K + k0) * 2 + (l & 3) * 16;
        GLOAD_LDS(src, (char*)As + c * 1024);
      }
      {
        const char* src = (const char*)W +
            ((size_t)(tN * 128 + c * 16 + (l >> 2)) * K + k0) * 2 + (l & 3) * 16;
        GLOAD_LDS(src, (char*)Bs + c * 1024);
      }
    }
    __syncthreads();
    bf16x8 af[4], bfr[4];
#pragma unroll
    for (int mi = 0; mi < 4; ++mi)
      af[mi] = *(const bf16x8*)&As[(wm * 64 + mi * 16 + lo) * 32 + hi * 8];
#pragma unroll
    for (int ni = 0; ni < 4; ++ni)
      bfr[ni] = *(const bf16x8*)&Bs[(wn * 64 + ni * 16 + lo) * 32 + hi * 8];
#pragma unroll
    for (int mi = 0; mi < 4; ++mi)
#pragma unroll
      for (int ni = 0; ni < 4; ++ni)
        acc[mi][ni] = __builtin_amdgcn_mfma_f32_16x16x32_bf16(af[mi], bfr[ni], acc[mi][ni], 0, 0, 0);
  }

  const int m_base = tM * 128 + wm * 64;
  const int o_base = tN * 128 + wn * 64;
#pragma unroll
  for (int mi = 0; mi < 4; ++mi) {
#pragma unroll
    for (int r = 0; r < 4; ++r) {
      const int mrow = m_base + mi * 16 + hi * 4 + r;
#pragma unroll
      for (int ni = 0; ni < 4; ++ni) {
        const int col = o_base + ni * 16 + lo;
        float v = acc[mi][ni][r];
        if (EPI == 0 || EPI == 1) {
          float pprt = __shfl_xor(v, 1);  // partner (d^1), same mrow
          if (mrow < MM) {
            int b = mrow / NN, n = mrow % NN;
            int h = col >> 6, d = col & 63;
            float cs = cosT[n * 64 + d], sn = sinT[n * 64 + d];
            float out = v * cs + (((d & 1) == 0) ? -pprt : pprt) * sn;
            if (EPI == 0) out *= 0.125f;
            obf[((size_t)(b * HH + h) * NPAD + n) * 64 + d] = (__bf16)out;
          }
        } else if (EPI == 2) {
          if (mrow < MM) {
            int b = mrow / NN, n = mrow % NN;
            int h = col >> 6, d = col & 63;
            obf[((size_t)(b * HH + h) * 64 + d) * NPAD + n] = (__bf16)v;
          }
        } else {
          if (mrow < MM) of32[(size_t)mrow * DIMM + col] = v + bp[col];
        }
      }
    }
  }
}

__device__ inline unsigned int pk2(float a, float b) {
  unsigned int ua = (unsigned int)__builtin_bit_cast(unsigned short, (__bf16)a);
  unsigned int ub = (unsigned int)__builtin_bit_cast(unsigned short, (__bf16)b);
  return ua | (ub << 16);
}

// ---------------- flash attention v3 ----------------
// Swapped QK^T (S^T in regs: lane = q-col, 16 k-partials in-register) ->
// shuffle-free softmax, no max-tracking (scores bounded ~|3|, fp32 exp safe),
// packed P^T via swizzled LDS, O^T accumulation with lane-local 1/l scaling.
__global__ __launch_bounds__(256) void attn_kernel(
    const __bf16* __restrict__ Qb, const __bf16* __restrict__ Kb,
    const __bf16* __restrict__ Vtb, const float* __restrict__ maskA,
    float* __restrict__ AO) {
  __shared__ __bf16 Ks[2][64 * 64];
  __shared__ __bf16 Vs[2][64 * 64];
  __shared__ unsigned int Plds[4][16 * 32];   // per-wave P^T tile: [16 q][32 k-pair words]
  const int tid = threadIdx.x;
  const int w = tid >> 6, l = tid & 63;
  const int lo = l & 15, hi = l >> 4;

  // XCD-aware swizzle: 1408 blocks, 8 XCDs, 176 consecutive orig-ids per XCD
  const int i = blockIdx.x;
  const int orig = (i & 7) * 176 + (i >> 3);
  const int bh = orig / NT;
  const int qt = orig % NT;
  const int b = bh >> 4;
  const int q0 = qt * 64 + w * 16;

  const __bf16* Qp = Qb + ((size_t)bh * NPAD + q0) * 64;
  bf16x8 qf0 = *(const bf16x8*)&Qp[lo * 64 + hi * 8];        // Q[q=lo][d hi*8..+7]
  bf16x8 qf1 = *(const bf16x8*)&Qp[lo * 64 + 32 + hi * 8];   // d-chunk 32..63

  // staging: LDS linear dest (wave-uniform base + lane*16), source pre-swizzled
  const int row8 = l >> 3;                    // row within 8-row stripe
  const int swz16 = ((l & 7) ^ row8) << 4;    // swizzled 16B-chunk byte offset
  const int lo7 = lo & 7;
  const int swzW = (lo & 7) << 2;             // P-tile word swizzle (4-word granular)

  f32x4 zero = {0.f, 0.f, 0.f, 0.f};
  f32x4 O[4];                                 // O^T: lane q=lo, d = n*16 + hi*4 + r
#pragma unroll
  for (int n = 0; n < 4; ++n) O[n] = zero;
  float lr = 0.f;                             // per-lane partial sum (q=lo)
  const float* mk = maskA + b * NPAD;

#define STAGE(buf, k0)                                                                   \
  {                                                                                      \
    _Pragma("unroll") for (int j = 0; j < 2; ++j) {                                      \
      const int rbase = (j * 4 + w) * 8;                                                 \
      const char* ksrc = (const char*)Kb +                                               \
          ((size_t)bh * NPAD + (k0) + rbase + row8) * 128 + swz16;                       \
      GLOAD_LDS(ksrc, (char*)&Ks[buf][0] + rbase * 128);                                 \
      const char* vsrc = (const char*)Vtb +                                              \
          ((size_t)(bh * 64 + rbase + row8) * NPAD + (k0)) * 2 + swz16;                  \
      GLOAD_LDS(vsrc, (char*)&Vs[buf][0] + rbase * 128);                                 \
    }                                                                                    \
  }

  STAGE(0, 0);
  __syncthreads();
  int cur = 0;

  for (int t = 0; t < NT; ++t) {
    if (t + 1 < NT) STAGE(cur ^ 1, (t + 1) * KVB);  // overlaps with compute below

    const __bf16* KB = &Ks[cur][0];
    const __bf16* VB = &Vs[cur][0];

    // mask (additive, 0 / -1e30): lane needs k = t*64 + c*16 + hi*4 + r
    f32x4 mv[4];
#pragma unroll
    for (int c = 0; c < 4; ++c) mv[c] = *(const f32x4*)&mk[t * KVB + c * 16 + hi * 4];

    // ---- S^T = K Q^T : lane holds col q=lo, rows k = c*16 + hi*4 + r ----
    f32x4 S[4];
    __builtin_amdgcn_s_setprio(1);
#pragma unroll
    for (int c = 0; c < 4; ++c) {
      const int kr = c * 16 + lo;
      bf16x8 kfa = *(const bf16x8*)&KB[kr * 64 + ((hi ^ lo7) * 8)];
      bf16x8 kfb = *(const bf16x8*)&KB[kr * 64 + (((hi + 4) ^ lo7) * 8)];
      f32x4 s = __builtin_amdgcn_mfma_f32_16x16x32_bf16(kfa, qf0, zero, 0, 0, 0);
      S[c]     = __builtin_amdgcn_mfma_f32_16x16x32_bf16(kfb, qf1, s, 0, 0, 0);
    }
    __builtin_amdgcn_s_setprio(0);

    // ---- softmax numerator (no max shift; |S| ~ 3 << 88) + pack P^T ----
    float rs = 0.f;
#pragma unroll
    for (int c = 0; c < 4; ++c) {
      float p0 = __expf(S[c][0] + mv[c][0]);
      float p1 = __expf(S[c][1] + mv[c][1]);
      float p2 = __expf(S[c][2] + mv[c][2]);
      float p3 = __expf(S[c][3] + mv[c][3]);
      rs += (p0 + p1) + (p2 + p3);
      uint2 pw = {pk2(p0, p1), pk2(p2, p3)};
      // word index w = 8c + 2hi (+1); row q = lo; swizzled by (lo&7)<<2
      *(uint2*)&Plds[w][lo * 32 + ((8 * c + 2 * hi) ^ swzW)] = pw;
    }
    lr += rs;

    // ---- B-frag read: lane needs P^T[k = cc*32 + hi*8 + j][q=lo] ----
    bf16x8 pf0 = *(const bf16x8*)&Plds[w][lo * 32 + ((4 * hi) ^ swzW)];
    bf16x8 pf1 = *(const bf16x8*)&Plds[w][lo * 32 + ((16 + 4 * hi) ^ swzW)];

    // ---- O^T += V^T P^T ----
    __builtin_amdgcn_s_setprio(1);
#pragma unroll
    for (int n = 0; n < 4; ++n) {
      const int vr = n * 16 + lo;
      bf16x8 vfa = *(const bf16x8*)&VB[vr * 64 + ((hi ^ lo7) * 8)];
      bf16x8 vfb = *(const bf16x8*)&VB[vr * 64 + (((hi + 4) ^ lo7) * 8)];
      O[n] = __builtin_amdgcn_mfma_f32_16x16x32_bf16(vfa, pf0, O[n], 0, 0, 0);
      O[n] = __builtin_amdgcn_mfma_f32_16x16x32_bf16(vfb, pf1, O[n], 0, 0, 0);
    }
    __builtin_amdgcn_s_setprio(0);

    __syncthreads();   // drains next-tile staging (vmcnt) + protects buffer swap
    cur ^= 1;
  }
#undef STAGE

  // final cross-lane denominator (once, not per tile)
  lr += __shfl_xor(lr, 16);
  lr += __shfl_xor(lr, 32);
  const float inv = 1.f / lr;

  const int h = bh & 15;
  const int token = q0 + lo;
  if (token < NN) {
    float* dst = AO + (size_t)(b * NN + token) * DIMM + h * 64 + hi * 4;
#pragma unroll
    for (int n = 0; n < 4; ++n) {
      f32x4 o = O[n];
      o[0] *= inv; o[1] *= inv; o[2] *= inv; o[3] *= inv;
      *(f32x4*)(dst + n * 16) = o;
    }
  }
}

// ---------------- LayerNorm over 1024, fp32 in, bf16 out ----------------
__global__ __launch_bounds__(256) void ln_kernel(
    const float* __restrict__ AO, const float* __restrict__ g,
    const float* __restrict__ be, __bf16* __restrict__ outb) {
  const int row = blockIdx.x;
  const int t = threadIdx.x;
  const float* x = AO + (size_t)row * DIMM;
  f32x4 v = ((const f32x4*)x)[t];
  float s = v[0] + v[1] + v[2] + v[3];
  float sq = v[0] * v[0] + v[1] * v[1] + v[2] * v[2] + v[3] * v[3];
#pragma unroll
  for (int m = 1; m < 64; m <<= 1) { s += __shfl_xor(s, m); sq += __shfl_xor(sq, m); }
  __shared__ float ss[4], ssq[4];
  int w = t >> 6, l = t & 63;
  if (l == 0) { ss[w] = s; ssq[w] = sq; }
  __syncthreads();
  s = ss[0] + ss[1] + ss[2] + ss[3];
  sq = ssq[0] + ssq[1] + ssq[2] + ssq[3];
  float mean = s * (1.f / 1024.f);
  float var = sq * (1.f / 1024.f) - mean * mean;
  float rstd = rsqrtf(var + 1e-5f);
  __bf16* o = outb + (size_t)row * DIMM + t * 4;
  const float* gp = g + t * 4;
  const float* bp2 = be + t * 4;
#pragma unroll
  for (int j = 0; j < 4; ++j) o[j] = (__bf16)((v[j] - mean) * rstd * gp[j] + bp2[j]);
}

// ---------------- launch ----------------
extern "C" void kernel_launch(void* const* d_in, const int* in_sizes, int n_in,
                              void* d_out, int out_size, void* d_ws, size_t ws_size,
                              hipStream_t stream) {
  const float* x   = (const float*)d_in[0];
  const float* val = (const float*)d_in[1];
  const void*  msk = d_in[2];
  const float* wq  = (const float*)d_in[3];
  const float* wk  = (const float*)d_in[4];
  const float* wv  = (const float*)d_in[5];
  const float* lng = (const float*)d_in[6];
  const float* lnb = (const float*)d_in[7];
  const float* wp  = (const float*)d_in[8];
  const float* bpv = (const float*)d_in[9];
  float* out = (float*)d_out;

  char* ws = (char*)d_ws;
  size_t off = 0;
  auto alloc = [&](size_t bytes) -> char* {
    char* p = ws + off;
    off += (bytes + 255) & ~(size_t)255;
    return p;
  };
  __bf16* xb  = (__bf16*)alloc((size_t)MPAD * 1024 * 2);  // also reused as LN output
  __bf16* vb  = (__bf16*)alloc((size_t)MPAD * 1536 * 2);
  __bf16* wqb = (__bf16*)alloc((size_t)1024 * 1024 * 2);
  __bf16* wkb = (__bf16*)alloc((size_t)1024 * 1536 * 2);
  __bf16* wvb = (__bf16*)alloc((size_t)1024 * 1536 * 2);
  __bf16* wpb = (__bf16*)alloc((size_t)1024 * 1024 * 2);
  __bf16* Qb  = (__bf16*)alloc((size_t)64 * NPAD * 64 * 2);
  __bf16* Kb  = (__bf16*)alloc((size_t)64 * NPAD * 64 * 2);
  __bf16* Vtb = (__bf16*)alloc((size_t)64 * 64 * NPAD * 2);
  float* AO   = (float*)alloc((size_t)MM * 1024 * 4);
  float* cosT = (float*)alloc((size_t)NN * 64 * 4);
  float* sinT = (float*)alloc((size_t)NN * 64 * 4);
  float* maskA = (float*)alloc((size_t)BB * NPAD * 4);

  // zero padded regions (pad rows of A-matrices; full Q/K/Vt so key-pads are benign)
  hipMemsetAsync(xb + (size_t)MM * 1024, 0, (size_t)(MPAD - MM) * 1024 * 2, stream);
  hipMemsetAsync(vb + (size_t)MM * 1536, 0, (size_t)(MPAD - MM) * 1536 * 2, stream);
  hipMemsetAsync(Qb, 0, (size_t)64 * NPAD * 64 * 2, stream);
  hipMemsetAsync(Kb, 0, (size_t)64 * NPAD * 64 * 2, stream);
  hipMemsetAsync(Vtb, 0, (size_t)64 * 64 * NPAD * 2, stream);

  cvt4<<<1024, 256, 0, stream>>>(x, xb, MM * 1024 / 4);
  cvt4<<<1024, 256, 0, stream>>>(val, vb, MM * 1536 / 4);
  cvt4<<<512, 256, 0, stream>>>(wq, wqb, 1024 * 1024 / 4);
  cvt4<<<512, 256, 0, stream>>>(wk, wkb, 1024 * 1536 / 4);
  cvt4<<<512, 256, 0, stream>>>(wv, wvb, 1024 * 1536 / 4);
  cvt4<<<512, 256, 0, stream>>>(wp, wpb, 1024 * 1024 / 4);
  rope_tables<<<(NN * 64 + 255) / 256, 256, 0, stream>>>(cosT, sinT);
  mask_prep<<<1, 256, 0, stream>>>(msk, maskA);

  dim3 gg(8, 43);
  gemm_bt<0><<<gg, 256, 0, stream>>>(xb, wqb, 1024, Qb, nullptr, cosT, sinT, nullptr);
  gemm_bt<1><<<gg, 256, 0, stream>>>(vb, wkb, 1536, Kb, nullptr, cosT, sinT, nullptr);
  gemm_bt<2><<<gg, 256, 0, stream>>>(vb, wvb, 1536, Vtb, nullptr, nullptr, nullptr, nullptr);

  attn_kernel<<<dim3(64 * NT), 256, 0, stream>>>(Qb, Kb, Vtb, maskA, AO);

  ln_kernel<<<MM, 256, 0, stream>>>(AO, lng, lnb, xb);  // reuse xb as LN output

  gemm_bt<3><<<gg, 256, 0, stream>>>(xb, wpb, 1024, nullptr, out, nullptr, nullptr, bpv);
}

// Round 4
// 302.980 us; speedup vs baseline: 1.3997x; 1.0369x over previous
//
#include <hip/hip_runtime.h>
#include <hip/hip_bf16.h>

#define BB 4
#define NN 1369
#define DIMM 1024
#define VDIMM 1536
#define HH 16
#define MM (BB*NN)      // 5476
#define MPAD 5504       // 43*128
#define NPAD 1408       // 22*64
#define KVB 64
#define NT (NPAD/KVB)   // 22
#define QSCALE 0.18028334f   // 0.125 * log2(e)

typedef __attribute__((ext_vector_type(4))) float f32x4;
typedef __attribute__((ext_vector_type(8))) __bf16 bf16x8;
typedef __attribute__((ext_vector_type(4))) __bf16 bf16x4;

#define GLOAD_LDS(gsrc, ldst) \
  __builtin_amdgcn_global_load_lds((const __attribute__((address_space(1))) unsigned int*)(gsrc), \
                                   (__attribute__((address_space(3))) unsigned int*)(ldst), 16, 0, 0)

// ---------------- elementwise fp32 -> bf16 (4-wide) ----------------
__global__ __launch_bounds__(256) void cvt4(const float* __restrict__ src,
                                            __bf16* __restrict__ dst, int n4) {
  int i = blockIdx.x * blockDim.x + threadIdx.x;
  int st = gridDim.x * blockDim.x;
  for (; i < n4; i += st) {
    f32x4 v = ((const f32x4*)src)[i];
    bf16x4 o;
    o[0] = (__bf16)v[0]; o[1] = (__bf16)v[1];
    o[2] = (__bf16)v[2]; o[3] = (__bf16)v[3];
    ((bf16x4*)dst)[i] = o;
  }
}

// ---------------- RoPE tables [1369][64] ----------------
__global__ __launch_bounds__(256) void rope_tables(float* __restrict__ cosT,
                                                   float* __restrict__ sinT) {
  int idx = blockIdx.x * blockDim.x + threadIdx.x;
  if (idx >= NN * 64) return;
  int n = idx >> 6, d = idx & 63;
  int r = n / 37, c = n % 37;
  int m = (d < 32) ? (d >> 1) : ((d - 32) >> 1);
  float p = (d < 32) ? (float)r : (float)c;
  float inv = powf(10000.f, -(float)m * (1.f / 16.f));
  float a = p * inv;
  cosT[idx] = cosf(a);
  sinT[idx] = sinf(a);
}

// ---------------- mask: detect dtype, canonicalize to ADDITIVE float [4][NPAD] ----------------
// on -> 0.0f ; off (or pad) -> -1e30f   (used inside exp2: exp2(-1e30) = 0)
__global__ __launch_bounds__(256) void mask_prep(const void* __restrict__ mask,
                                                 float* __restrict__ maskA) {
  __shared__ int flags[2];
  int t = threadIdx.x;
  if (t < 2) flags[t] = 0;
  __syncthreads();
  const unsigned int* mw = (const unsigned int*)mask;
  for (int i = t; i < NN; i += blockDim.x) {   // first 1369 words: in-bounds for every dtype
    unsigned int w = mw[i];
    if (w == 0x3F800000u) atomicOr(&flags[1], 1);
    else if (w > 1u) atomicOr(&flags[0], 1);
  }
  __syncthreads();
  int md = flags[1] ? 2 : (flags[0] ? 1 : 0);  // 0=int32, 1=bool bytes, 2=float32
  const unsigned char* mb = (const unsigned char*)mask;
  const float* mf = (const float*)mask;
  for (int i = t; i < BB * NPAD; i += blockDim.x) {
    int b = i / NPAD, key = i % NPAD;
    float v = -1e30f;
    if (key < NN) {
      int idx = b * NN + key;
      bool on = (md == 0) ? (mw[idx] != 0u) : (md == 1) ? (mb[idx] != 0) : (mf[idx] != 0.f);
      if (on) v = 0.f;
    }
    maskA[i] = v;
  }
}

// ---------------- GEMM C[m,o] = sum_i A[m,i]*W[o,i], bf16 in, fp32 acc ----------------
// TN = 128: 4 waves in 2x2 (wave tile 64x64);  TN = 64: 4 waves stacked in M (wave tile 32x64)
// EPI 0: RoPE * QSCALE -> Q[b][h][n][d]          (TN=64,  N=1024)
// EPI 1: cols<1024: RoPE -> K ; cols>=1024: -> Vt (TN=128, N=2048 merged KV)
// EPI 3: +bp -> fp32 out                          (TN=64,  N=1024)
template <int TN, int EPI>
__global__ __launch_bounds__(256) void gemm_bt(
    const __bf16* __restrict__ A, const __bf16* __restrict__ W, int K,
    __bf16* __restrict__ obf, __bf16* __restrict__ obf2, float* __restrict__ of32,
    const float* __restrict__ cosT, const float* __restrict__ sinT,
    const float* __restrict__ bp) {
  constexpr int MI = (TN == 128) ? 4 : 2;
  __shared__ __bf16 As[128 * 32];
  __shared__ __bf16 Bs[TN * 32];
  const int tid = threadIdx.x;
  const int w = tid >> 6, l = tid & 63;
  const int tM = blockIdx.y, tN = blockIdx.x;
  const int wm = (TN == 128) ? (w >> 1) : w;
  const int wn = (TN == 128) ? (w & 1) : 0;
  const int wmo = wm * ((TN == 128) ? 64 : 32);
  const int wno = wn * 64;
  const int lo = l & 15, hi = l >> 4;

  f32x4 zero = {0.f, 0.f, 0.f, 0.f};
  f32x4 acc[MI][4];
#pragma unroll
  for (int i = 0; i < MI; ++i)
#pragma unroll
    for (int j = 0; j < 4; ++j) acc[i][j] = zero;

  for (int k0 = 0; k0 < K; k0 += 32) {
    __syncthreads();
#pragma unroll
    for (int j = 0; j < 2; ++j) {
      int c = j * 4 + w;
      const char* src = (const char*)A +
          ((size_t)(tM * 128 + c * 16 + (l >> 2)) * K + k0) * 2 + (l & 3) * 16;
      GLOAD_LDS(src, (char*)As + c * 1024);
    }
    if (TN == 128) {
#pragma unroll
      for (int j = 0; j < 2; ++j) {
        int c = j * 4 + w;
        const char* src = (const char*)W +
            ((size_t)(tN * 128 + c * 16 + (l >> 2)) * K + k0) * 2 + (l & 3) * 16;
        GLOAD_LDS(src, (char*)Bs + c * 1024);
      }
    } else {
      const char* src = (const char*)W +
          ((size_t)(tN * 64 + w * 16 + (l >> 2)) * K + k0) * 2 + (l & 3) * 16;
      GLOAD_LDS(src, (char*)Bs + w * 1024);
    }
    __syncthreads();
    bf16x8 af[MI], bfr[4];
#pragma unroll
    for (int mi = 0; mi < MI; ++mi)
      af[mi] = *(const bf16x8*)&As[(wmo + mi * 16 + lo) * 32 + hi * 8];
#pragma unroll
    for (int ni = 0; ni < 4; ++ni)
      bfr[ni] = *(const bf16x8*)&Bs[(wno + ni * 16 + lo) * 32 + hi * 8];
#pragma unroll
    for (int mi = 0; mi < MI; ++mi)
#pragma unroll
      for (int ni = 0; ni < 4; ++ni)
        acc[mi][ni] = __builtin_amdgcn_mfma_f32_16x16x32_bf16(af[mi], bfr[ni], acc[mi][ni], 0, 0, 0);
  }

  const int m_base = tM * 128 + wmo;
  const int o_base = tN * TN + wno;
  const bool isK = (EPI == 1) && (tN * TN < 1024);   // block-uniform for TN=128
#pragma unroll
  for (int mi = 0; mi < MI; ++mi) {
#pragma unroll
    for (int r = 0; r < 4; ++r) {
      const int mrow = m_base + mi * 16 + hi * 4 + r;
#pragma unroll
      for (int ni = 0; ni < 4; ++ni) {
        const int col = o_base + ni * 16 + lo;
        float v = acc[mi][ni][r];
        if (EPI == 0) {
          float pprt = __shfl_xor(v, 1);  // partner (d^1), same mrow
          if (mrow < MM) {
            int b = mrow / NN, n = mrow % NN;
            int h = col >> 6, d = col & 63;
            float cs = cosT[n * 64 + d], sn = sinT[n * 64 + d];
            float out = (v * cs + (((d & 1) == 0) ? -pprt : pprt) * sn) * QSCALE;
            obf[((size_t)(b * HH + h) * NPAD + n) * 64 + d] = (__bf16)out;
          }
        } else if (EPI == 1) {
          if (isK) {
            float pprt = __shfl_xor(v, 1);
            if (mrow < MM) {
              int b = mrow / NN, n = mrow % NN;
              int h = col >> 6, d = col & 63;
              float cs = cosT[n * 64 + d], sn = sinT[n * 64 + d];
              float out = v * cs + (((d & 1) == 0) ? -pprt : pprt) * sn;
              obf[((size_t)(b * HH + h) * NPAD + n) * 64 + d] = (__bf16)out;
            }
          } else {
            if (mrow < MM) {
              int b = mrow / NN, n = mrow % NN;
              int o2 = col - 1024;
              int h = o2 >> 6, d = o2 & 63;
              obf2[((size_t)(b * HH + h) * 64 + d) * NPAD + n] = (__bf16)v;
            }
          }
        } else {
          if (mrow < MM) of32[(size_t)mrow * DIMM + col] = v + bp[col];
        }
      }
    }
  }
}

__device__ inline unsigned int pk2(float a, float b) {
  unsigned int ua = (unsigned int)__builtin_bit_cast(unsigned short, (__bf16)a);
  unsigned int ub = (unsigned int)__builtin_bit_cast(unsigned short, (__bf16)b);
  return ua | (ub << 16);
}

// ---------------- flash attention v3 ----------------
// Swapped QK^T (S^T in regs: lane = q-col, 16 k-partials in-register) ->
// shuffle-free softmax, no max-tracking (scores bounded, fp32 exp safe; log2e
// pre-folded into Q so p = exp2(S + mask)), packed P^T via swizzled LDS,
// O^T accumulation with lane-local 1/l scaling.
__global__ __launch_bounds__(256) void attn_kernel(
    const __bf16* __restrict__ Qb, const __bf16* __restrict__ Kb,
    const __bf16* __restrict__ Vtb, const float* __restrict__ maskA,
    float* __restrict__ AO) {
  __shared__ __bf16 Ks[2][64 * 64];
  __shared__ __bf16 Vs[2][64 * 64];
  __shared__ unsigned int Plds[4][16 * 32];   // per-wave P^T tile: [16 q][32 k-pair words]
  const int tid = threadIdx.x;
  const int w = tid >> 6, l = tid & 63;
  const int lo = l & 15, hi = l >> 4;

  // XCD-aware swizzle: 1408 blocks, 8 XCDs, 176 consecutive orig-ids per XCD
  const int i = blockIdx.x;
  const int orig = (i & 7) * 176 + (i >> 3);
  const int bh = orig / NT;
  const int qt = orig % NT;
  const int b = bh >> 4;
  const int q0 = qt * 64 + w * 16;

  const __bf16* Qp = Qb + ((size_t)bh * NPAD + q0) * 64;
  bf16x8 qf0 = *(const bf16x8*)&Qp[lo * 64 + hi * 8];        // Q[q=lo][d hi*8..+7]
  bf16x8 qf1 = *(const bf16x8*)&Qp[lo * 64 + 32 + hi * 8];   // d-chunk 32..63

  // staging: LDS linear dest (wave-uniform base + lane*16), source pre-swizzled
  const int row8 = l >> 3;                    // row within 8-row stripe
  const int swz16 = ((l & 7) ^ row8) << 4;    // swizzled 16B-chunk byte offset
  const int lo7 = lo & 7;
  const int swzW = (lo & 7) << 2;             // P-tile word swizzle (4-word granular)

  f32x4 zero = {0.f, 0.f, 0.f, 0.f};
  f32x4 O[4];                                 // O^T: lane q=lo, d = n*16 + hi*4 + r
#pragma unroll
  for (int n = 0; n < 4; ++n) O[n] = zero;
  float lr = 0.f;                             // per-lane partial sum (q=lo)
  const float* mk = maskA + b * NPAD;

#define STAGE(buf, k0)                                                                   \
  {                                                                                      \
    _Pragma("unroll") for (int j = 0; j < 2; ++j) {                                      \
      const int rbase = (j * 4 + w) * 8;                                                 \
      const char* ksrc = (const char*)Kb +                                               \
          ((size_t)bh * NPAD + (k0) + rbase + row8) * 128 + swz16;                       \
      GLOAD_LDS(ksrc, (char*)&Ks[buf][0] + rbase * 128);                                 \
      const char* vsrc = (const char*)Vtb +                                              \
          ((size_t)(bh * 64 + rbase + row8) * NPAD + (k0)) * 2 + swz16;                  \
      GLOAD_LDS(vsrc, (char*)&Vs[buf][0] + rbase * 128);                                 \
    }                                                                                    \
  }

  STAGE(0, 0);
  __syncthreads();
  int cur = 0;

  for (int t = 0; t < NT; ++t) {
    if (t + 1 < NT) STAGE(cur ^ 1, (t + 1) * KVB);  // overlaps with compute below

    const __bf16* KB = &Ks[cur][0];
    const __bf16* VB = &Vs[cur][0];

    // mask (additive, 0 / -1e30): lane needs k = t*64 + c*16 + hi*4 + r
    f32x4 mv[4];
#pragma unroll
    for (int c = 0; c < 4; ++c) mv[c] = *(const f32x4*)&mk[t * KVB + c * 16 + hi * 4];

    // ---- S^T = K Q^T : lane holds col q=lo, rows k = c*16 + hi*4 + r ----
    f32x4 S[4];
    __builtin_amdgcn_s_setprio(1);
#pragma unroll
    for (int c = 0; c < 4; ++c) {
      const int kr = c * 16 + lo;
      bf16x8 kfa = *(const bf16x8*)&KB[kr * 64 + ((hi ^ lo7) * 8)];
      bf16x8 kfb = *(const bf16x8*)&KB[kr * 64 + (((hi + 4) ^ lo7) * 8)];
      f32x4 s = __builtin_amdgcn_mfma_f32_16x16x32_bf16(kfa, qf0, zero, 0, 0, 0);
      S[c]     = __builtin_amdgcn_mfma_f32_16x16x32_bf16(kfb, qf1, s, 0, 0, 0);
    }
    __builtin_amdgcn_s_setprio(0);

    // ---- softmax numerator: p = exp2(S + mask)  (log2e folded into Q) ----
    float rs = 0.f;
#pragma unroll
    for (int c = 0; c < 4; ++c) {
      float p0 = exp2f(S[c][0] + mv[c][0]);
      float p1 = exp2f(S[c][1] + mv[c][1]);
      float p2 = exp2f(S[c][2] + mv[c][2]);
      float p3 = exp2f(S[c][3] + mv[c][3]);
      rs += (p0 + p1) + (p2 + p3);
      uint2 pw = {pk2(p0, p1), pk2(p2, p3)};
      // word index w = 8c + 2hi (+1); row q = lo; swizzled by (lo&7)<<2
      *(uint2*)&Plds[w][lo * 32 + ((8 * c + 2 * hi) ^ swzW)] = pw;
    }
    lr += rs;

    // ---- B-frag read: lane needs P^T[k = cc*32 + hi*8 + j][q=lo] ----
    bf16x8 pf0 = *(const bf16x8*)&Plds[w][lo * 32 + ((4 * hi) ^ swzW)];
    bf16x8 pf1 = *(const bf16x8*)&Plds[w][lo * 32 + ((16 + 4 * hi) ^ swzW)];

    // ---- O^T += V^T P^T ----
    __builtin_amdgcn_s_setprio(1);
#pragma unroll
    for (int n = 0; n < 4; ++n) {
      const int vr = n * 16 + lo;
      bf16x8 vfa = *(const bf16x8*)&VB[vr * 64 + ((hi ^ lo7) * 8)];
      bf16x8 vfb = *(const bf16x8*)&VB[vr * 64 + (((hi + 4) ^ lo7) * 8)];
      O[n] = __builtin_amdgcn_mfma_f32_16x16x32_bf16(vfa, pf0, O[n], 0, 0, 0);
      O[n] = __builtin_amdgcn_mfma_f32_16x16x32_bf16(vfb, pf1, O[n], 0, 0, 0);
    }
    __builtin_amdgcn_s_setprio(0);

    __syncthreads();   // drains next-tile staging (vmcnt) + protects buffer swap
    cur ^= 1;
  }
#undef STAGE

  // final cross-lane denominator (once, not per tile; lanes l, l^16, l^32 share q=lo)
  lr += __shfl_xor(lr, 16);
  lr += __shfl_xor(lr, 32);
  const float inv = 1.f / lr;

  const int h = bh & 15;
  const int token = q0 + lo;
  if (token < NN) {
    float* dst = AO + (size_t)(b * NN + token) * DIMM + h * 64 + hi * 4;
#pragma unroll
    for (int n = 0; n < 4; ++n) {
      f32x4 o = O[n];
      o[0] *= inv; o[1] *= inv; o[2] *= inv; o[3] *= inv;
      *(f32x4*)(dst + n * 16) = o;
    }
  }
}

// ---------------- LayerNorm over 1024, fp32 in, bf16 out ----------------
__global__ __launch_bounds__(256) void ln_kernel(
    const float* __restrict__ AO, const float* __restrict__ g,
    const float* __restrict__ be, __bf16* __restrict__ outb) {
  const int row = blockIdx.x;
  const int t = threadIdx.x;
  const float* x = AO + (size_t)row * DIMM;
  f32x4 v = ((const f32x4*)x)[t];
  float s = v[0] + v[1] + v[2] + v[3];
  float sq = v[0] * v[0] + v[1] * v[1] + v[2] * v[2] + v[3] * v[3];
#pragma unroll
  for (int m = 1; m < 64; m <<= 1) { s += __shfl_xor(s, m); sq += __shfl_xor(sq, m); }
  __shared__ float ss[4], ssq[4];
  int w = t >> 6, l = t & 63;
  if (l == 0) { ss[w] = s; ssq[w] = sq; }
  __syncthreads();
  s = ss[0] + ss[1] + ss[2] + ss[3];
  sq = ssq[0] + ssq[1] + ssq[2] + ssq[3];
  float mean = s * (1.f / 1024.f);
  float var = sq * (1.f / 1024.f) - mean * mean;
  float rstd = rsqrtf(var + 1e-5f);
  __bf16* o = outb + (size_t)row * DIMM + t * 4;
  const float* gp = g + t * 4;
  const float* bp2 = be + t * 4;
#pragma unroll
  for (int j = 0; j < 4; ++j) o[j] = (__bf16)((v[j] - mean) * rstd * gp[j] + bp2[j]);
}

// ---------------- launch ----------------
extern "C" void kernel_launch(void* const* d_in, const int* in_sizes, int n_in,
                              void* d_out, int out_size, void* d_ws, size_t ws_size,
                              hipStream_t stream) {
  const float* x   = (const float*)d_in[0];
  const float* val = (const float*)d_in[1];
  const void*  msk = d_in[2];
  const float* wq  = (const float*)d_in[3];
  const float* wk  = (const float*)d_in[4];
  const float* wv  = (const float*)d_in[5];
  const float* lng = (const float*)d_in[6];
  const float* lnb = (const float*)d_in[7];
  const float* wp  = (const float*)d_in[8];
  const float* bpv = (const float*)d_in[9];
  float* out = (float*)d_out;

  char* ws = (char*)d_ws;
  size_t off = 0;
  auto alloc = [&](size_t bytes) -> char* {
    char* p = ws + off;
    off += (bytes + 255) & ~(size_t)255;
    return p;
  };
  __bf16* xb   = (__bf16*)alloc((size_t)MPAD * 1024 * 2);  // also reused as LN output
  __bf16* vb   = (__bf16*)alloc((size_t)MPAD * 1536 * 2);
  __bf16* wqb  = (__bf16*)alloc((size_t)1024 * 1024 * 2);
  __bf16* wkvb = (__bf16*)alloc((size_t)2048 * 1536 * 2);  // wk ‖ wv (rows 0..1023 / 1024..2047)
  __bf16* wpb  = (__bf16*)alloc((size_t)1024 * 1024 * 2);
  __bf16* Qb   = (__bf16*)alloc((size_t)64 * NPAD * 64 * 2);
  __bf16* Kb   = (__bf16*)alloc((size_t)64 * NPAD * 64 * 2);
  __bf16* Vtb  = (__bf16*)alloc((size_t)64 * 64 * NPAD * 2);
  float* AO    = (float*)alloc((size_t)MM * 1024 * 4);
  float* cosT  = (float*)alloc((size_t)NN * 64 * 4);
  float* sinT  = (float*)alloc((size_t)NN * 64 * 4);
  float* maskA = (float*)alloc((size_t)BB * NPAD * 4);

  // zero padded regions (pad rows of A-matrices; full Q/K/Vt so key-pads are benign)
  hipMemsetAsync(xb + (size_t)MM * 1024, 0, (size_t)(MPAD - MM) * 1024 * 2, stream);
  hipMemsetAsync(vb + (size_t)MM * 1536, 0, (size_t)(MPAD - MM) * 1536 * 2, stream);
  hipMemsetAsync(Qb, 0, (size_t)64 * NPAD * 64 * 2, stream);
  hipMemsetAsync(Kb, 0, (size_t)64 * NPAD * 64 * 2, stream);
  hipMemsetAsync(Vtb, 0, (size_t)64 * 64 * NPAD * 2, stream);

  cvt4<<<1024, 256, 0, stream>>>(x, xb, MM * 1024 / 4);
  cvt4<<<1024, 256, 0, stream>>>(val, vb, MM * 1536 / 4);
  cvt4<<<512, 256, 0, stream>>>(wq, wqb, 1024 * 1024 / 4);
  cvt4<<<512, 256, 0, stream>>>(wk, wkvb, 1024 * 1536 / 4);
  cvt4<<<512, 256, 0, stream>>>(wv, wkvb + (size_t)1024 * 1536, 1024 * 1536 / 4);
  cvt4<<<512, 256, 0, stream>>>(wp, wpb, 1024 * 1024 / 4);
  rope_tables<<<(NN * 64 + 255) / 256, 256, 0, stream>>>(cosT, sinT);
  mask_prep<<<1, 256, 0, stream>>>(msk, maskA);

  // Q: N=1024, TN=64 -> 16x43 = 688 blocks
  gemm_bt<64, 0><<<dim3(16, 43), 256, 0, stream>>>(xb, wqb, 1024, Qb, nullptr, nullptr, cosT, sinT, nullptr);
  // merged KV: N=2048, TN=128 -> 16x43 = 688 blocks
  gemm_bt<128, 1><<<dim3(16, 43), 256, 0, stream>>>(vb, wkvb, 1536, Kb, Vtb, nullptr, cosT, sinT, nullptr);

  attn_kernel<<<dim3(64 * NT), 256, 0, stream>>>(Qb, Kb, Vtb, maskA, AO);

  ln_kernel<<<MM, 256, 0, stream>>>(AO, lng, lnb, xb);  // reuse xb as LN output

  // out-proj: N=1024, TN=64 -> 688 blocks
  gemm_bt<64, 3><<<dim3(16, 43), 256, 0, stream>>>(xb, wpb, 1024, nullptr, nullptr, out, nullptr, nullptr, bpv);
}